// Round 1
// baseline (567.485 us; speedup 1.0000x reference)
//
#include <hip/hip_runtime.h>
#include <math.h>

#define B_ROWS 16384
#define D_DIM  2048
#define H_DIM  512

typedef __attribute__((ext_vector_type(8))) short  s16x8;  // 8 bf16
typedef __attribute__((ext_vector_type(4))) float  f32x4;  // MFMA acc

union U8 { unsigned short us[8]; s16x8 v; };

static __device__ __forceinline__ unsigned short f2bf(float f) {
    unsigned u = __float_as_uint(f);
    u += 0x7FFFu + ((u >> 16) & 1u);   // RNE (no NaN inputs here)
    return (unsigned short)(u >> 16);
}

// ---------------- Kernel 0: pack W1 -> bf16 hi/lo in MFMA B-fragment order ----------------
// Fragment layout (16x16x32): lane l holds B[k=(l>>4)*8+j][n=l&15], j=0..7.
// Wp[type][s=k>>5][Nt=n>>4][lane][j], 2 types x 64 s x 32 Nt x 64 lanes x 8 bf16 = 4 MB.
__global__ __launch_bounds__(256) void pack_w1(
    const float* __restrict__ W1, unsigned short* __restrict__ Wp)
{
    const int gid = blockIdx.x * 256 + threadIdx.x;   // 131072 = 256 k-octets x 512 n
    const int ko = gid >> 9;          // k-octet 0..255
    const int n  = gid & 511;
    U8 h8, l8;
    #pragma unroll
    for (int j = 0; j < 8; ++j) {
        const float w = W1[(size_t)(ko * 8 + j) * H_DIM + n];
        const unsigned short h = f2bf(w);
        const float hf = __uint_as_float((unsigned)h << 16);
        h8.us[j] = h;
        l8.us[j] = f2bf(w - hf);
    }
    const int s    = ko >> 2;
    const int lane = (n & 15) | ((ko & 3) << 4);
    const int Nt   = n >> 4;
    const size_t baseH = ((((size_t)0 * 64 + s) * 32 + Nt) * 64 + lane) * 8;
    const size_t baseL = ((((size_t)1 * 64 + s) * 32 + Nt) * 64 + lane) * 8;
    *(s16x8*)(Wp + baseH) = h8.v;
    *(s16x8*)(Wp + baseL) = l8.v;
}

// ---------------- Kernel 0b: pack x -> bf16 hi/lo in MFMA A-fragment order ----------------
// A-fragment (16x16x32): lane l holds A[m=l&15][k=(l>>4)*8+j], j=0..7.
// Xp[type][rt=row>>4][s=k>>5][lane][j]; 2 x 1024 x 64 x 64 x 8 shorts = 134.2 MB.
// gid = (rt*64 + s)*64 + l  ->  dest base is simply gid*8 (fully coalesced store).
__global__ __launch_bounds__(256) void pack_x(
    const float* __restrict__ x, unsigned short* __restrict__ Xp)
{
    const int gid = blockIdx.x * 256 + threadIdx.x;   // 4,194,304 threads
    const int l  = gid & 63;
    const int s  = (gid >> 6) & 63;
    const int rt = gid >> 12;                          // 0..1023
    const float* p = x + (size_t)(rt * 16 + (l & 15)) * D_DIM + s * 32 + (l >> 4) * 8;
    const float4 a = *(const float4*)p;
    const float4 b = *(const float4*)(p + 4);
    U8 h8, l8;
    const float xv[8] = {a.x, a.y, a.z, a.w, b.x, b.y, b.z, b.w};
    #pragma unroll
    for (int j = 0; j < 8; ++j) {
        const unsigned short h = f2bf(xv[j]);
        h8.us[j] = h;
        l8.us[j] = f2bf(xv[j] - __uint_as_float((unsigned)h << 16));
    }
    const size_t base = (size_t)gid * 8;
    *(s16x8*)(Xp + base) = h8.v;                              // hi plane
    *(s16x8*)(Xp + 33554432ull + base) = l8.v;                // lo plane (+64 MB)
}

// ---------------- Kernel 1: predictor GEMM, barrier-free pure frag-stream ----------------
// Grid 256 blocks x 512 threads (8 waves). Block owns 64 rows x all 512 cols; wave Nw owns
// cols [Nw*64, Nw*64+64). A/B fragments pre-packed (pack_x / pack_w1) -> per step just
// 16 global_load_dwordx4 + 48 MFMA (3-product split: hh + lh + hl; lo*lo ~2^-18, dropped).
// No LDS, no __syncthreads -> compiler pipelines loads across steps with counted vmcnt.
__global__ __launch_bounds__(512, 2) void predictor_gemm(
    const unsigned short* __restrict__ Xp, const unsigned short* __restrict__ Wp,
    const float* __restrict__ b1, const float* __restrict__ W2,
    double* __restrict__ logit)
{
    const int tid = threadIdx.x;
    const int l   = tid & 63;
    const int Nw  = tid >> 6;          // 0..7
    const int bx  = blockIdx.x;        // 0..255
    const int rowBase = bx * 64;
    const int NtBase  = Nw * 4;

    const s16x8* XpV = (const s16x8*)Xp;   // [2][1024][64][64] v-units
    const s16x8* WpV = (const s16x8*)Wp;   // [2][64][32][64]   v-units

    // A base: ((bx*4+mt)*64 + s)*64 + l   (s-stride 64 v-units, mt-stride 4096)
    const s16x8* aH = XpV + ((size_t)(bx * 4) * 64) * 64 + l;
    const s16x8* aL = aH + 1024ull * 64 * 64;
    // B base: (s*32 + NtBase+nt)*64 + l   (s-stride 2048 v-units, nt-stride 64)
    const s16x8* bH = WpV + (size_t)NtBase * 64 + l;
    const s16x8* bL = bH + 64ull * 32 * 64;

    f32x4 acc[4][4];
    #pragma unroll
    for (int mt = 0; mt < 4; ++mt)
        #pragma unroll
        for (int nt = 0; nt < 4; ++nt)
            acc[mt][nt] = {0.f, 0.f, 0.f, 0.f};

    s16x8 Ah[4], Al[4], Bh[4], Bl[4];
    #pragma unroll
    for (int mt = 0; mt < 4; ++mt) {
        Ah[mt] = aH[(size_t)mt * 4096];
        Al[mt] = aL[(size_t)mt * 4096];
    }
    #pragma unroll
    for (int nt = 0; nt < 4; ++nt) {
        Bh[nt] = bH[nt * 64];
        Bl[nt] = bL[nt * 64];
    }

    for (int s = 0; s < 64; ++s) {
        s16x8 AhN[4], AlN[4], BhN[4], BlN[4];
        if (s < 63) {
            #pragma unroll
            for (int mt = 0; mt < 4; ++mt) {
                AhN[mt] = aH[(size_t)mt * 4096 + (s + 1) * 64];
                AlN[mt] = aL[(size_t)mt * 4096 + (s + 1) * 64];
            }
            #pragma unroll
            for (int nt = 0; nt < 4; ++nt) {
                BhN[nt] = bH[(s + 1) * 2048 + nt * 64];
                BlN[nt] = bL[(s + 1) * 2048 + nt * 64];
            }
        }

        // 48 MFMAs: (hi+lo)*(hi+lo) minus lo*lo
        #pragma unroll
        for (int mt = 0; mt < 4; ++mt)
            #pragma unroll
            for (int nt = 0; nt < 4; ++nt) {
                acc[mt][nt] = __builtin_amdgcn_mfma_f32_16x16x32_bf16(Ah[mt], Bh[nt], acc[mt][nt], 0, 0, 0);
                acc[mt][nt] = __builtin_amdgcn_mfma_f32_16x16x32_bf16(Al[mt], Bh[nt], acc[mt][nt], 0, 0, 0);
                acc[mt][nt] = __builtin_amdgcn_mfma_f32_16x16x32_bf16(Ah[mt], Bl[nt], acc[mt][nt], 0, 0, 0);
            }

        if (s < 63) {
            #pragma unroll
            for (int i = 0; i < 4; ++i) {
                Ah[i] = AhN[i]; Al[i] = AlN[i];
                Bh[i] = BhN[i]; Bl[i] = BlN[i];
            }
        }
    }

    // epilogue: +b1, relu, fp64 dot with W2, cross-lane reduce, atomic
    float  b1v[4];
    double w2v[4];
    #pragma unroll
    for (int nt = 0; nt < 4; ++nt) {
        const int j = (NtBase + nt) * 16 + (l & 15);
        b1v[nt] = b1[j];
        w2v[nt] = (double)W2[j];
    }
    #pragma unroll
    for (int mt = 0; mt < 4; ++mt)
        #pragma unroll
        for (int reg = 0; reg < 4; ++reg) {
            double p = 0.0;
            #pragma unroll
            for (int nt = 0; nt < 4; ++nt) {
                const float h = acc[mt][nt][reg] + b1v[nt];
                if (h > 0.0f) p = fma((double)h, w2v[nt], p);
            }
            #pragma unroll
            for (int m2 = 1; m2 < 16; m2 <<= 1) p += __shfl_xor(p, m2, 64);
            if ((l & 15) == 0)
                atomicAdd(&logit[rowBase + mt * 16 + ((l >> 4) & 3) * 4 + reg], p);
        }
}

// ------------- Kernel 2: wave-per-row radix select + writeback (barrier-free) -------------
// One wave owns one row: 32 values/lane in VGPRs, per-wave 256-bin LDS histogram with
// 4-way sub-counter replication (lane&3) to cut hot-bin same-address serialization.
__global__ __launch_bounds__(256) void select_and_write(
    const float* __restrict__ x, const float* __restrict__ b2,
    const double* __restrict__ logit,
    float* __restrict__ out_sparse, float* __restrict__ out_mask,
    float* __restrict__ out_sparsity, float* __restrict__ out_actual,
    double* __restrict__ l1rows)
{
    __shared__ int hist[4][1024];    // per wave: 256 bins x 4 sub-counters

    const int tid = threadIdx.x;
    const int w = tid >> 6, l = tid & 63;
    const int row = blockIdx.x * 4 + w;
    int* hw = hist[w];

    const float4* x4 = (const float4*)(x + (size_t)row * D_DIM);
    float4 vv[8];
    #pragma unroll
    for (int i = 0; i < 8; ++i) vv[i] = x4[i * 64 + l];   // elems (i*64+l)*4..+3

    // k from logit (all lanes compute identically; wave-uniform)
    const double L = logit[row] + (double)b2[0];
    const double sig = 1.0 / (1.0 + exp(-L));
    const double s = 0.05 + 0.25 * sig;                 // MIN_S + (MAX_S-MIN_S)*sig
    int k = (int)rint(2048.0 * (1.0 - s));              // half-even == np.round
    if (k < 1) k = 1;
    if (k > 2048) k = 2048;
    if (l == 0) out_sparsity[row] = (float)s;

    int krem = k;                 // rank of k-th SMALLEST |x|
    unsigned prefix = 0;

    #pragma unroll
    for (int pass = 0; pass < 4; ++pass) {
        const int shift = 24 - pass * 8;
        const unsigned pmask = (pass == 0) ? 0u : (0xFFFFFFFFu << (shift + 8));

        #pragma unroll
        for (int j = 0; j < 4; ++j)
            ((int4*)hw)[l + 64 * j] = int4{0, 0, 0, 0};
        __builtin_amdgcn_wave_barrier();
        __threadfence_block();   // lgkmcnt drain; wave-synchronous, no s_barrier

        #pragma unroll
        for (int i = 0; i < 8; ++i) {
            const float qq[4] = {vv[i].x, vv[i].y, vv[i].z, vv[i].w};
            #pragma unroll
            for (int c = 0; c < 4; ++c) {
                const unsigned ub = __float_as_uint(qq[c]) & 0x7FFFFFFFu;
                if (pass == 0 || (ub & pmask) == prefix)
                    atomicAdd(&hw[((ub >> shift) & 255) * 4 + (l & 3)], 1);
            }
        }
        __builtin_amdgcn_wave_barrier();
        __threadfence_block();

        // scan: lane l owns bins 4l..4l+3 (each bin = one int4 of sub-counters)
        int b_[4], tot = 0;
        #pragma unroll
        for (int j = 0; j < 4; ++j) {
            const int4 c4 = ((const int4*)hw)[4 * l + j];
            b_[j] = c4.x + c4.y + c4.z + c4.w;
            tot += b_[j];
        }
        int sc = tot;
        #pragma unroll
        for (int off = 1; off < 64; off <<= 1) {
            const int n = __shfl_up(sc, off);
            if (l >= off) sc += n;
        }
        int cum = sc - tot;           // elems in bins < 4l
        int found = 0;
        #pragma unroll
        for (int j = 0; j < 4; ++j) {
            if (krem > cum && krem <= cum + b_[j])
                found = ((4 * l + j) << 12) | (krem - cum);   // one lane-j only
            cum += b_[j];
        }
        #pragma unroll
        for (int m2 = 1; m2 < 64; m2 <<= 1) found |= __shfl_xor(found, m2);
        prefix |= ((unsigned)(found >> 12)) << shift;
        krem = found & 0xFFF;
    }
    const unsigned thr = prefix;   // exact bit pattern of k-th smallest |x|

    // writeback: mask = (|x| > thr), bitwise-identical to reference compare
    float4* os4 = (float4*)(out_sparse + (size_t)row * D_DIM);
    float4* om4 = (float4*)(out_mask   + (size_t)row * D_DIM);
    int cnt = 0;
    double lp = 0.0;
    #pragma unroll
    for (int i = 0; i < 8; ++i) {
        const float qq[4] = {vv[i].x, vv[i].y, vv[i].z, vv[i].w};
        float sq[4], mq[4];
        #pragma unroll
        for (int c = 0; c < 4; ++c) {
            const unsigned ub = __float_as_uint(qq[c]) & 0x7FFFFFFFu;
            const bool keep = (ub > thr);
            mq[c] = keep ? 1.0f : 0.0f;
            sq[c] = keep ? qq[c] : 0.0f;
            cnt += keep ? 1 : 0;
            if (keep) lp += (double)fabsf(qq[c]);
        }
        os4[i * 64 + l] = float4{sq[0], sq[1], sq[2], sq[3]};
        om4[i * 64 + l] = float4{mq[0], mq[1], mq[2], mq[3]};
    }
    #pragma unroll
    for (int m2 = 1; m2 < 64; m2 <<= 1) {
        lp  += __shfl_xor(lp, m2);
        cnt += __shfl_xor(cnt, m2);
    }
    if (l == 0) {
        l1rows[row] = lp;
        out_actual[row] = (float)cnt * (1.0f / 2048.0f);
    }
}

// ---------------- Kernel 3: reduce row L1 sums -> l1_reg ----------------
__global__ __launch_bounds__(256) void finalize_l1(
    const double* __restrict__ l1rows, float* __restrict__ out_l1)
{
    __shared__ double sh[256];
    double s = 0.0;
    for (int i = threadIdx.x; i < B_ROWS; i += 256) s += l1rows[i];
    sh[threadIdx.x] = s;
    __syncthreads();
    for (int st = 128; st > 0; st >>= 1) {
        if (threadIdx.x < st) sh[threadIdx.x] += sh[threadIdx.x + st];
        __syncthreads();
    }
    if (threadIdx.x == 0) out_l1[0] = (float)(sh[0] / (double)B_ROWS);
}

extern "C" void kernel_launch(void* const* d_in, const int* in_sizes, int n_in,
                              void* d_out, int out_size, void* d_ws, size_t ws_size,
                              hipStream_t stream) {
    const float* x  = (const float*)d_in[0];
    const float* W1 = (const float*)d_in[1];
    const float* b1 = (const float*)d_in[2];
    const float* W2 = (const float*)d_in[3];
    const float* b2 = (const float*)d_in[4];

    float* out = (float*)d_out;
    float* out_sparse   = out;                                   // B*D
    float* out_mask     = out + (size_t)B_ROWS * D_DIM;          // B*D
    float* out_sparsity = out + 2ull * B_ROWS * D_DIM;           // B
    float* out_actual   = out_sparsity + B_ROWS;                 // B
    float* out_l1       = out_actual + B_ROWS;                   // 1

    double* logit  = (double*)d_ws;                        // B doubles (atomics)
    double* l1rows = logit + B_ROWS;                       // B doubles
    unsigned short* Wp = (unsigned short*)(l1rows + B_ROWS);  // 4 MB packed W1 hi/lo

    // Packed x (hi/lo A-fragments): 134,217,728 B. Prefer workspace; if the workspace
    // is too small, alias onto out_mask (exactly B*D*4 B) — pack_x writes it, the GEMM
    // reads it, and select_and_write fully overwrites it afterwards (stream-ordered).
    const size_t fixedBytes = 2ull * B_ROWS * sizeof(double)      // logit + l1rows
                            + 2ull * 64 * 32 * 512 * sizeof(unsigned short); // Wp 4 MB
    const size_t XP_BYTES = 2ull * B_ROWS * D_DIM * sizeof(unsigned short);
    unsigned short* Xp;
    if (ws_size >= fixedBytes + XP_BYTES)
        Xp = (unsigned short*)((char*)d_ws + fixedBytes);
    else
        Xp = (unsigned short*)out_mask;

    hipMemsetAsync(d_ws, 0, (size_t)B_ROWS * sizeof(double), stream);

    pack_w1<<<512, 256, 0, stream>>>(W1, Wp);
    pack_x<<<16384, 256, 0, stream>>>(x, Xp);
    predictor_gemm<<<256, 512, 0, stream>>>(Xp, Wp, b1, W2, logit);
    select_and_write<<<B_ROWS / 4, 256, 0, stream>>>(x, b2, logit, out_sparse, out_mask,
                                                     out_sparsity, out_actual, l1rows);
    finalize_l1<<<1, 256, 0, stream>>>(l1rows, out_l1);
}

// Round 2
// 505.735 us; speedup vs baseline: 1.1221x; 1.1221x over previous
//
#include <hip/hip_runtime.h>
#include <math.h>

#define B_ROWS 16384
#define D_DIM  2048
#define H_DIM  512

typedef __attribute__((ext_vector_type(8))) short  s16x8;  // 8 bf16
typedef __attribute__((ext_vector_type(4))) float  f32x4;  // MFMA acc

union U8 { unsigned short us[8]; s16x8 v; };
union U4 { unsigned short us[4]; short4 v; };

static __device__ __forceinline__ unsigned short f2bf(float f) {
    unsigned u = __float_as_uint(f);
    u += 0x7FFFu + ((u >> 16) & 1u);   // RNE (no NaN inputs here)
    return (unsigned short)(u >> 16);
}

// ---------------- Kernel 0: pack W1 -> bf16 hi/lo in MFMA B-fragment order ----------------
// Fragment layout (16x16x32): lane l holds B[k=(l>>4)*8+j][n=l&15], j=0..7.
// Wp[type][s=k>>5][Nt=n>>4][lane][j], 2 types x 64 s x 32 Nt x 64 lanes x 8 bf16 = 4 MB.
__global__ __launch_bounds__(256) void pack_w1(
    const float* __restrict__ W1, unsigned short* __restrict__ Wp)
{
    const int gid = blockIdx.x * 256 + threadIdx.x;   // 131072 = 256 k-octets x 512 n
    const int ko = gid >> 9;          // k-octet 0..255
    const int n  = gid & 511;
    U8 h8, l8;
    #pragma unroll
    for (int j = 0; j < 8; ++j) {
        const float w = W1[(size_t)(ko * 8 + j) * H_DIM + n];
        const unsigned short h = f2bf(w);
        const float hf = __uint_as_float((unsigned)h << 16);
        h8.us[j] = h;
        l8.us[j] = f2bf(w - hf);
    }
    const int s    = ko >> 2;
    const int lane = (n & 15) | ((ko & 3) << 4);
    const int Nt   = n >> 4;
    const size_t baseH = ((((size_t)0 * 64 + s) * 32 + Nt) * 64 + lane) * 8;
    const size_t baseL = ((((size_t)1 * 64 + s) * 32 + Nt) * 64 + lane) * 8;
    *(s16x8*)(Wp + baseH) = h8.v;
    *(s16x8*)(Wp + baseL) = l8.v;
}

// ---------------- Kernel 1: predictor GEMM via bf16 MFMA, 3-product split ----------------
// Block: 64 rows x ALL 512 cols, 512 threads (8 waves, one per 64-col slice).
// x read ONCE (no column-half duplication). A staged via LDS dbuf with in-kernel hi/lo
// conversion spread over all 512 threads (4 floats each); B frags direct global->VGPR
// from packed Wp (L2-resident). (xh+xl)(wh+wl) minus xl*wl: 48 MFMA/step, fp32-GEMM-
// equivalent accuracy (lo*lo ~2^-18 relative; verified bit-stable absmax in round 1).
__global__ __launch_bounds__(512, 2) void predictor_gemm(
    const float* __restrict__ x, const unsigned short* __restrict__ Wp,
    const float* __restrict__ b1, const float* __restrict__ W2,
    double* __restrict__ logit)
{
    // [buf][type][Mt*512 + lane*8 + j]: 2 x 2 x 2048 shorts = 16 KB
    __shared__ __align__(16) unsigned short Abuf[2][2][2048];

    const int tid = threadIdx.x;
    const int l   = tid & 63;
    const int Nw  = tid >> 6;          // 0..7
    const int bx  = blockIdx.x;
    const int rowBase = bx * 64;
    const int NtBase  = Nw * 4;

    // staging role: thread -> (row sm, half-octet sh), 4 consecutive k-values
    const int sm = tid >> 3;           // 0..63
    const int sh = tid & 7;            // 0..7 -> k = s*32 + sh*4 .. +3
    const float* xp = x + (size_t)(rowBase + sm) * D_DIM + sh * 4;
    const int stIdx = (sm >> 4) * 512 + (((sm & 15) | ((sh >> 1) << 4)) << 3) + (sh & 1) * 4;
    unsigned short* stH[2] = {&Abuf[0][0][stIdx], &Abuf[1][0][stIdx]};
    unsigned short* stL[2] = {&Abuf[0][1][stIdx], &Abuf[1][1][stIdx]};

    const s16x8* WpV = (const s16x8*)Wp;

    f32x4 acc[4][4];
    #pragma unroll
    for (int mt = 0; mt < 4; ++mt)
        #pragma unroll
        for (int nt = 0; nt < 4; ++nt)
            acc[mt][nt] = {0.f, 0.f, 0.f, 0.f};

    // prologue: stage step 0 into buf 0, preload step-0 B frags
    {
        const float4 v = *(const float4*)(xp);
        const float xv[4] = {v.x, v.y, v.z, v.w};
        U4 h4, l4;
        #pragma unroll
        for (int j = 0; j < 4; ++j) {
            const unsigned short h = f2bf(xv[j]);
            h4.us[j] = h;
            l4.us[j] = f2bf(xv[j] - __uint_as_float((unsigned)h << 16));
        }
        *(short4*)stH[0] = h4.v;
        *(short4*)stL[0] = l4.v;
    }
    s16x8 Bh[4], Bl[4];
    #pragma unroll
    for (int nt = 0; nt < 4; ++nt) {
        Bh[nt] = WpV[((0 * 64 + 0) * 32 + NtBase + nt) * 64 + l];
        Bl[nt] = WpV[((1 * 64 + 0) * 32 + NtBase + nt) * 64 + l];
    }
    __syncthreads();

    for (int s = 0; s < 64; ++s) {
        const int cur = s & 1, nxt = cur ^ 1;
        s16x8 BhN[4], BlN[4];
        float4 xn;
        if (s < 63) {
            #pragma unroll
            for (int nt = 0; nt < 4; ++nt) {
                BhN[nt] = WpV[((0 * 64 + (s + 1)) * 32 + NtBase + nt) * 64 + l];
                BlN[nt] = WpV[((1 * 64 + (s + 1)) * 32 + NtBase + nt) * 64 + l];
            }
            xn = *(const float4*)(xp + (s + 1) * 32);
        }

        s16x8 Ah[4], Al[4];
        #pragma unroll
        for (int mt = 0; mt < 4; ++mt) {
            Ah[mt] = *(const s16x8*)&Abuf[cur][0][mt * 512 + l * 8];
            Al[mt] = *(const s16x8*)&Abuf[cur][1][mt * 512 + l * 8];
        }

        // 48 MFMAs: hh + lh + hl (lo*lo dropped)
        #pragma unroll
        for (int mt = 0; mt < 4; ++mt)
            #pragma unroll
            for (int nt = 0; nt < 4; ++nt) {
                acc[mt][nt] = __builtin_amdgcn_mfma_f32_16x16x32_bf16(Ah[mt], Bh[nt], acc[mt][nt], 0, 0, 0);
                acc[mt][nt] = __builtin_amdgcn_mfma_f32_16x16x32_bf16(Al[mt], Bh[nt], acc[mt][nt], 0, 0, 0);
                acc[mt][nt] = __builtin_amdgcn_mfma_f32_16x16x32_bf16(Ah[mt], Bl[nt], acc[mt][nt], 0, 0, 0);
            }

        if (s < 63) {
            const float xv[4] = {xn.x, xn.y, xn.z, xn.w};
            U4 h4, l4;
            #pragma unroll
            for (int j = 0; j < 4; ++j) {
                const unsigned short h = f2bf(xv[j]);
                h4.us[j] = h;
                l4.us[j] = f2bf(xv[j] - __uint_as_float((unsigned)h << 16));
            }
            *(short4*)stH[nxt] = h4.v;
            *(short4*)stL[nxt] = l4.v;
            #pragma unroll
            for (int nt = 0; nt < 4; ++nt) { Bh[nt] = BhN[nt]; Bl[nt] = BlN[nt]; }
        }
        __syncthreads();
    }

    // epilogue: +b1, relu, fp64 dot with W2, cross-lane reduce, atomic
    float  b1v[4];
    double w2v[4];
    #pragma unroll
    for (int nt = 0; nt < 4; ++nt) {
        const int j = (NtBase + nt) * 16 + (l & 15);
        b1v[nt] = b1[j];
        w2v[nt] = (double)W2[j];
    }
    #pragma unroll
    for (int mt = 0; mt < 4; ++mt)
        #pragma unroll
        for (int reg = 0; reg < 4; ++reg) {
            double p = 0.0;
            #pragma unroll
            for (int nt = 0; nt < 4; ++nt) {
                const float h = acc[mt][nt][reg] + b1v[nt];
                if (h > 0.0f) p = fma((double)h, w2v[nt], p);
            }
            #pragma unroll
            for (int m2 = 1; m2 < 16; m2 <<= 1) p += __shfl_xor(p, m2, 64);
            if ((l & 15) == 0)
                atomicAdd(&logit[rowBase + mt * 16 + ((l >> 4) & 3) * 4 + reg], p);
        }
}

// ------------- Kernel 2: wave-per-row radix select + writeback (barrier-free) -------------
// One wave owns one row: 32 values/lane in VGPRs, per-wave 256-bin LDS histogram with
// 4-way sub-counter replication (lane&3) to cut hot-bin same-address serialization.
__global__ __launch_bounds__(256) void select_and_write(
    const float* __restrict__ x, const float* __restrict__ b2,
    const double* __restrict__ logit,
    float* __restrict__ out_sparse, float* __restrict__ out_mask,
    float* __restrict__ out_sparsity, float* __restrict__ out_actual,
    double* __restrict__ l1rows)
{
    __shared__ int hist[4][1024];    // per wave: 256 bins x 4 sub-counters

    const int tid = threadIdx.x;
    const int w = tid >> 6, l = tid & 63;
    const int row = blockIdx.x * 4 + w;
    int* hw = hist[w];

    const float4* x4 = (const float4*)(x + (size_t)row * D_DIM);
    float4 vv[8];
    #pragma unroll
    for (int i = 0; i < 8; ++i) vv[i] = x4[i * 64 + l];   // elems (i*64+l)*4..+3

    // k from logit (all lanes compute identically; wave-uniform)
    const double L = logit[row] + (double)b2[0];
    const double sig = 1.0 / (1.0 + exp(-L));
    const double s = 0.05 + 0.25 * sig;                 // MIN_S + (MAX_S-MIN_S)*sig
    int k = (int)rint(2048.0 * (1.0 - s));              // half-even == np.round
    if (k < 1) k = 1;
    if (k > 2048) k = 2048;
    if (l == 0) out_sparsity[row] = (float)s;

    int krem = k;                 // rank of k-th SMALLEST |x|
    unsigned prefix = 0;

    #pragma unroll
    for (int pass = 0; pass < 4; ++pass) {
        const int shift = 24 - pass * 8;
        const unsigned pmask = (pass == 0) ? 0u : (0xFFFFFFFFu << (shift + 8));

        #pragma unroll
        for (int j = 0; j < 4; ++j)
            ((int4*)hw)[l + 64 * j] = int4{0, 0, 0, 0};
        __builtin_amdgcn_wave_barrier();
        __threadfence_block();   // lgkmcnt drain; wave-synchronous, no s_barrier

        #pragma unroll
        for (int i = 0; i < 8; ++i) {
            const float qq[4] = {vv[i].x, vv[i].y, vv[i].z, vv[i].w};
            #pragma unroll
            for (int c = 0; c < 4; ++c) {
                const unsigned ub = __float_as_uint(qq[c]) & 0x7FFFFFFFu;
                if (pass == 0 || (ub & pmask) == prefix)
                    atomicAdd(&hw[((ub >> shift) & 255) * 4 + (l & 3)], 1);
            }
        }
        __builtin_amdgcn_wave_barrier();
        __threadfence_block();

        // scan: lane l owns bins 4l..4l+3 (each bin = one int4 of sub-counters)
        int b_[4], tot = 0;
        #pragma unroll
        for (int j = 0; j < 4; ++j) {
            const int4 c4 = ((const int4*)hw)[4 * l + j];
            b_[j] = c4.x + c4.y + c4.z + c4.w;
            tot += b_[j];
        }
        int sc = tot;
        #pragma unroll
        for (int off = 1; off < 64; off <<= 1) {
            const int n = __shfl_up(sc, off);
            if (l >= off) sc += n;
        }
        int cum = sc - tot;           // elems in bins < 4l
        int found = 0;
        #pragma unroll
        for (int j = 0; j < 4; ++j) {
            if (krem > cum && krem <= cum + b_[j])
                found = ((4 * l + j) << 12) | (krem - cum);   // one lane-j only
            cum += b_[j];
        }
        #pragma unroll
        for (int m2 = 1; m2 < 64; m2 <<= 1) found |= __shfl_xor(found, m2);
        prefix |= ((unsigned)(found >> 12)) << shift;
        krem = found & 0xFFF;
    }
    const unsigned thr = prefix;   // exact bit pattern of k-th smallest |x|

    // writeback: mask = (|x| > thr), bitwise-identical to reference compare
    float4* os4 = (float4*)(out_sparse + (size_t)row * D_DIM);
    float4* om4 = (float4*)(out_mask   + (size_t)row * D_DIM);
    int cnt = 0;
    double lp = 0.0;
    #pragma unroll
    for (int i = 0; i < 8; ++i) {
        const float qq[4] = {vv[i].x, vv[i].y, vv[i].z, vv[i].w};
        float sq[4], mq[4];
        #pragma unroll
        for (int c = 0; c < 4; ++c) {
            const unsigned ub = __float_as_uint(qq[c]) & 0x7FFFFFFFu;
            const bool keep = (ub > thr);
            mq[c] = keep ? 1.0f : 0.0f;
            sq[c] = keep ? qq[c] : 0.0f;
            cnt += keep ? 1 : 0;
            if (keep) lp += (double)fabsf(qq[c]);
        }
        os4[i * 64 + l] = float4{sq[0], sq[1], sq[2], sq[3]};
        om4[i * 64 + l] = float4{mq[0], mq[1], mq[2], mq[3]};
    }
    #pragma unroll
    for (int m2 = 1; m2 < 64; m2 <<= 1) {
        lp  += __shfl_xor(lp, m2);
        cnt += __shfl_xor(cnt, m2);
    }
    if (l == 0) {
        l1rows[row] = lp;
        out_actual[row] = (float)cnt * (1.0f / 2048.0f);
    }
}

// ---------------- Kernel 3: reduce row L1 sums -> l1_reg ----------------
__global__ __launch_bounds__(256) void finalize_l1(
    const double* __restrict__ l1rows, float* __restrict__ out_l1)
{
    __shared__ double sh[256];
    double s = 0.0;
    for (int i = threadIdx.x; i < B_ROWS; i += 256) s += l1rows[i];
    sh[threadIdx.x] = s;
    __syncthreads();
    for (int st = 128; st > 0; st >>= 1) {
        if (threadIdx.x < st) sh[threadIdx.x] += sh[threadIdx.x + st];
        __syncthreads();
    }
    if (threadIdx.x == 0) out_l1[0] = (float)(sh[0] / (double)B_ROWS);
}

extern "C" void kernel_launch(void* const* d_in, const int* in_sizes, int n_in,
                              void* d_out, int out_size, void* d_ws, size_t ws_size,
                              hipStream_t stream) {
    const float* x  = (const float*)d_in[0];
    const float* W1 = (const float*)d_in[1];
    const float* b1 = (const float*)d_in[2];
    const float* W2 = (const float*)d_in[3];
    const float* b2 = (const float*)d_in[4];

    float* out = (float*)d_out;
    float* out_sparse   = out;                                   // B*D
    float* out_mask     = out + (size_t)B_ROWS * D_DIM;          // B*D
    float* out_sparsity = out + 2ull * B_ROWS * D_DIM;           // B
    float* out_actual   = out_sparsity + B_ROWS;                 // B
    float* out_l1       = out_actual + B_ROWS;                   // 1

    double* logit  = (double*)d_ws;                        // B doubles (atomics)
    double* l1rows = logit + B_ROWS;                       // B doubles
    unsigned short* Wp = (unsigned short*)(l1rows + B_ROWS);  // 4 MB packed W1 hi/lo

    hipMemsetAsync(d_ws, 0, (size_t)B_ROWS * sizeof(double), stream);

    pack_w1<<<512, 256, 0, stream>>>(W1, Wp);
    predictor_gemm<<<B_ROWS / 64, 512, 0, stream>>>(x, Wp, b1, W2, logit);
    select_and_write<<<B_ROWS / 4, 256, 0, stream>>>(x, b2, logit, out_sparse, out_mask,
                                                     out_sparsity, out_actual, l1rows);
    finalize_l1<<<1, 256, 0, stream>>>(l1rows, out_l1);
}